// Round 2
// 621.435 us; speedup vs baseline: 1.0222x; 1.0222x over previous
//
#include <hip/hip_runtime.h>
#include <hip/hip_bf16.h>

#define NN 100000
#define EE 1600000
#define IND 128
#define HD 128
#define EM 64
#define KC 100
#define BN_EPS 1e-5f
#define BN_ROWS 128
#define BKT 512
#define NBK ((NN + BKT - 1) / BKT)      // 196 buckets (dst >> 9)
#define SROWS 32                         // softmax rows per block

// ---------------- bucketed CSR build ----------------
__global__ void k_zero256(int* __restrict__ gcnt){
  int t = threadIdx.x;
  if (t < NBK) gcnt[t] = 0;
}

__global__ __launch_bounds__(256) void k_bhist(const int* __restrict__ ei,
                                               int* __restrict__ gcnt){
  __shared__ int lh[NBK];
  int t = threadIdx.x;
  for (int i = t; i < NBK; i += 256) lh[i] = 0;
  __syncthreads();
  int e = blockIdx.x*2048 + t;
  #pragma unroll
  for (int i = 0; i < 8; ++i, e += 256)
    if (e < EE) atomicAdd(&lh[ei[EE + e] >> 9], 1);
  __syncthreads();
  for (int i = t; i < NBK; i += 256)
    if (lh[i]) atomicAdd(&gcnt[i], lh[i]);
}

__global__ void k_bscan(const int* __restrict__ gcnt, int* __restrict__ bbase,
                        int* __restrict__ gcur, int* __restrict__ rowptr){
  __shared__ int ls[256];
  int t = threadIdx.x;
  int v = (t < NBK) ? gcnt[t] : 0;
  ls[t] = v; __syncthreads();
  #pragma unroll
  for (int off = 1; off < 256; off <<= 1){
    int x = (t >= off) ? ls[t-off] : 0;
    __syncthreads();
    ls[t] += x;
    __syncthreads();
  }
  int ex = ls[t] - v;
  if (t < NBK){ bbase[t] = ex; gcur[t] = ex; }
  if (t == NBK-1) bbase[NBK] = ex + v;   // == EE
  if (t == 0) rowptr[NN] = EE;
}

__global__ __launch_bounds__(256) void k_part(const int* __restrict__ ei,
                                              int* __restrict__ gcur,
                                              int2* __restrict__ pbuf){
  __shared__ int lh[NBK];
  __shared__ int lcur[NBK];
  int t = threadIdx.x;
  for (int i = t; i < NBK; i += 256) lh[i] = 0;
  __syncthreads();
  int e0 = blockIdx.x*2048;
  #pragma unroll
  for (int i = 0; i < 8; ++i){
    int e = e0 + i*256 + t;
    if (e < EE) atomicAdd(&lh[ei[EE + e] >> 9], 1);
  }
  __syncthreads();
  for (int i = t; i < NBK; i += 256)
    lcur[i] = lh[i] ? atomicAdd(&gcur[i], lh[i]) : 0;
  __syncthreads();
  #pragma unroll
  for (int i = 0; i < 8; ++i){
    int e = e0 + i*256 + t;
    if (e < EE){
      int s = ei[e], d = ei[EE + e];
      int pos = atomicAdd(&lcur[d >> 9], 1);
      pbuf[pos] = make_int2(s, d);
    }
  }
}

// one block per bucket: LDS hist + local scan + local-cursor fill
__global__ __launch_bounds__(256) void k_bfill(const int2* __restrict__ pbuf,
                                               const int* __restrict__ bbase,
                                               int* __restrict__ rowptr,
                                               int* __restrict__ esrc,
                                               float* __restrict__ dis){
  __shared__ int lcnt[BKT];
  __shared__ int ls[256];
  int b = blockIdx.x, t = threadIdx.x;
  int n0 = b*BKT;
  int e0 = bbase[b], e1 = bbase[b+1];
  lcnt[2*t] = 0; lcnt[2*t+1] = 0;
  __syncthreads();
  for (int e = e0 + t; e < e1; e += 256)
    atomicAdd(&lcnt[pbuf[e].y - n0], 1);
  __syncthreads();
  int v0 = lcnt[2*t], v1 = lcnt[2*t+1];
  int s = v0 + v1;
  ls[t] = s; __syncthreads();
  #pragma unroll
  for (int off = 1; off < 256; off <<= 1){
    int x = (t >= off) ? ls[t-off] : 0;
    __syncthreads();
    ls[t] += x;
    __syncthreads();
  }
  int run = ls[t] - s;                    // exclusive prefix (pairs)
  if (n0 + 2*t < NN){
    rowptr[n0 + 2*t] = e0 + run;
    dis[n0 + 2*t] = rsqrtf((float)v0 + 1.0f);
  }
  if (n0 + 2*t + 1 < NN){
    rowptr[n0 + 2*t + 1] = e0 + run + v0;
    dis[n0 + 2*t + 1] = rsqrtf((float)v1 + 1.0f);
  }
  lcnt[2*t] = run; lcnt[2*t+1] = run + v0;  // relative cursors
  __syncthreads();
  for (int e = e0 + t; e < e1; e += 256){
    int2 p = pbuf[e];
    int pos = atomicAdd(&lcnt[p.y - n0], 1);
    esrc[e0 + pos] = p.x;
  }
}

// ------- GEMM1: h1s = (x @ W1) * dis[row]  (pre-scaled by src norm) ---------
__global__ __launch_bounds__(256) void k_gemm1(const float* __restrict__ x,
                                               const float* __restrict__ W1,
                                               const float* __restrict__ dis,
                                               float* __restrict__ h1s){
  __shared__ float xs[64][IND];
  int t = threadIdx.x;
  int rbase = blockIdx.x * 64;
  #pragma unroll
  for (int i = 0; i < 8; ++i){
    int flat = i*256 + t;
    int r = flat >> 5;
    int q = flat & 31;
    float4 v = make_float4(0.f,0.f,0.f,0.f);
    if (rbase + r < NN) v = *(const float4*)&x[(size_t)(rbase+r)*IND + q*4];
    *(float4*)&xs[r][q*4] = v;
  }
  __syncthreads();
  int c0 = (t & 31) * 4;
  int r0 = (t >> 5) * 8;
  float acc[8][4] = {};
  #pragma unroll 4
  for (int k4 = 0; k4 < IND/4; ++k4){
    float4 w0 = *(const float4*)&W1[(k4*4+0)*HD + c0];
    float4 w1 = *(const float4*)&W1[(k4*4+1)*HD + c0];
    float4 w2 = *(const float4*)&W1[(k4*4+2)*HD + c0];
    float4 w3 = *(const float4*)&W1[(k4*4+3)*HD + c0];
    #pragma unroll
    for (int g = 0; g < 8; ++g){
      float4 xv = *(const float4*)&xs[r0+g][k4*4];
      acc[g][0] += xv.x*w0.x + xv.y*w1.x + xv.z*w2.x + xv.w*w3.x;
      acc[g][1] += xv.x*w0.y + xv.y*w1.y + xv.z*w2.y + xv.w*w3.y;
      acc[g][2] += xv.x*w0.z + xv.y*w1.z + xv.z*w2.z + xv.w*w3.z;
      acc[g][3] += xv.x*w0.w + xv.y*w1.w + xv.z*w2.w + xv.w*w3.w;
    }
  }
  #pragma unroll
  for (int g = 0; g < 8; ++g){
    int r = rbase + r0 + g;
    if (r < NN){
      float sc = dis[r];
      float4 o;
      o.x = acc[g][0]*sc; o.y = acc[g][1]*sc;
      o.z = acc[g][2]*sc; o.w = acc[g][3]*sc;
      *(float4*)&h1s[(size_t)r*HD + c0] = o;
    }
  }
}

// ---- GCN1 gather: 1 wave/node, 64-edge coalesced index preload.
// All __shfl broadcasts run under wave-uniform control flow (m is uniform
// per wave); per-half work split is applied to the shfl INDEX only, and the
// tail predicates only the load/accumulate. (ds_bpermute returns 0 from
// EXEC-off lanes — divergent-trip shfl was the round-1 bug.)
__global__ __launch_bounds__(256) void k_gather1(
    const int* __restrict__ rowptr, const int* __restrict__ esrc,
    const float* __restrict__ dis, const float* __restrict__ h1s,
    const float* __restrict__ b1, float* __restrict__ hg){
  int w = threadIdx.x >> 6, lane = threadIdx.x & 63;
  int d = blockIdx.x*4 + w;
  int half = lane >> 5;
  int q = lane & 31;
  float dd = dis[d];
  float4 a = make_float4(0.f,0.f,0.f,0.f);
  if (half == 0){
    // self loop: dd*dd*h1[d] == dd * h1s[d]; the dd factor is applied at the end
    a = *(const float4*)&h1s[(size_t)d*HD + q*4];
  }
  int p0 = rowptr[d], p1 = rowptr[d+1];
  for (int base = p0; base < p1; base += 64){
    int idx = base + lane;
    int s_l = (idx < p1) ? esrc[idx] : 0;   // coalesced: 64 edge indices at once
    int m = min(64, p1 - base);             // wave-uniform
    int mm8 = m & ~7;
    // main: uniform trip count; 4 independent gathers in flight per half
    for (int jb = 0; jb < mm8; jb += 8){
      int s0 = __shfl(s_l, jb + half);
      int s1 = __shfl(s_l, jb + 2 + half);
      int s2 = __shfl(s_l, jb + 4 + half);
      int s3 = __shfl(s_l, jb + 6 + half);
      float4 v0 = *(const float4*)&h1s[(size_t)s0*HD + q*4];
      float4 v1 = *(const float4*)&h1s[(size_t)s1*HD + q*4];
      float4 v2 = *(const float4*)&h1s[(size_t)s2*HD + q*4];
      float4 v3 = *(const float4*)&h1s[(size_t)s3*HD + q*4];
      a.x += v0.x + v1.x + v2.x + v3.x;
      a.y += v0.y + v1.y + v2.y + v3.y;
      a.z += v0.z + v1.z + v2.z + v3.z;
      a.w += v0.w + v1.w + v2.w + v3.w;
    }
    // tail (<8): uniform loop; shfl before the predicate, accumulate inside
    for (int j = mm8; j < m; j += 2){
      int jj = j + half;                    // jj <= m <= 63 here
      int s = __shfl(s_l, jj);
      if (jj < m){
        float4 v = *(const float4*)&h1s[(size_t)s*HD + q*4];
        a.x += v.x; a.y += v.y; a.z += v.z; a.w += v.w;
      }
    }
  }
  a.x += __shfl_xor(a.x, 32); a.y += __shfl_xor(a.y, 32);
  a.z += __shfl_xor(a.z, 32); a.w += __shfl_xor(a.w, 32);
  if (half == 0){
    float4 b = *(const float4*)&b1[q*4];
    a.x = a.x*dd + b.x; a.y = a.y*dd + b.y;
    a.z = a.z*dd + b.z; a.w = a.w*dd + b.w;
    *(float4*)&hg[(size_t)d*HD + q*4] = a;
  }
}

// ---------------- BatchNorm stats + coefficients ----------------
__global__ void k_stats_zero(float* __restrict__ sums, float* __restrict__ sumsq){
  int i = threadIdx.x;
  if (i < HD){ sums[i] = 0.f; sumsq[i] = 0.f; }
}

__global__ void k_bn_stats(const float* __restrict__ hg, float* __restrict__ sums,
                           float* __restrict__ sumsq){
  int j = threadIdx.x;
  int r0 = blockIdx.x * BN_ROWS;
  int r1 = min(r0 + BN_ROWS, NN);
  float s = 0.f, q = 0.f;
  for (int r = r0; r < r1; ++r){
    float v = hg[(size_t)r*HD + j];
    s += v; q += v*v;
  }
  atomicAdd(&sums[j], s);
  atomicAdd(&sumsq[j], q);
}

__global__ void k_bn_coef(const float* __restrict__ sums, const float* __restrict__ sumsq,
                          const float* __restrict__ gamma, const float* __restrict__ beta,
                          float* __restrict__ scale, float* __restrict__ shift){
  int j = threadIdx.x;
  const float invN = 1.0f/(float)NN;
  float mu  = sums[j]*invN;
  float var = sumsq[j]*invN - mu*mu;
  float sc  = gamma[j]*rsqrtf(var+BN_EPS);
  scale[j] = sc;
  shift[j] = beta[j] - mu*sc;
}

// ------- GEMM2: h2s = (relu(bn(hg)) @ W2) * dis[row] ----------
__global__ __launch_bounds__(256) void k_gemm2(const float* __restrict__ hg,
                                               const float* __restrict__ W2,
                                               const float* __restrict__ scale,
                                               const float* __restrict__ shift,
                                               const float* __restrict__ dis,
                                               float* __restrict__ h2s){
  __shared__ float hs[64][HD];
  int t = threadIdx.x;
  int rbase = blockIdx.x * 64;
  #pragma unroll
  for (int i = 0; i < 8; ++i){
    int flat = i*256 + t;
    int r = flat >> 5;
    int q = flat & 31;
    float4 v = make_float4(0.f,0.f,0.f,0.f);
    if (rbase + r < NN){
      v = *(const float4*)&hg[(size_t)(rbase+r)*HD + q*4];
      float4 sc = *(const float4*)&scale[q*4];
      float4 sh = *(const float4*)&shift[q*4];
      v.x = fmaxf(v.x*sc.x + sh.x, 0.f);
      v.y = fmaxf(v.y*sc.y + sh.y, 0.f);
      v.z = fmaxf(v.z*sc.z + sh.z, 0.f);
      v.w = fmaxf(v.w*sc.w + sh.w, 0.f);
    }
    *(float4*)&hs[r][q*4] = v;
  }
  __syncthreads();
  int c0 = (t & 15) * 4;
  int r0 = (t >> 4) * 4;
  float acc[4][4] = {};
  #pragma unroll 4
  for (int k4 = 0; k4 < HD/4; ++k4){
    float4 w0 = *(const float4*)&W2[(k4*4+0)*EM + c0];
    float4 w1 = *(const float4*)&W2[(k4*4+1)*EM + c0];
    float4 w2 = *(const float4*)&W2[(k4*4+2)*EM + c0];
    float4 w3 = *(const float4*)&W2[(k4*4+3)*EM + c0];
    #pragma unroll
    for (int g = 0; g < 4; ++g){
      float4 xv = *(const float4*)&hs[r0+g][k4*4];
      acc[g][0] += xv.x*w0.x + xv.y*w1.x + xv.z*w2.x + xv.w*w3.x;
      acc[g][1] += xv.x*w0.y + xv.y*w1.y + xv.z*w2.y + xv.w*w3.y;
      acc[g][2] += xv.x*w0.z + xv.y*w1.z + xv.z*w2.z + xv.w*w3.z;
      acc[g][3] += xv.x*w0.w + xv.y*w1.w + xv.z*w2.w + xv.w*w3.w;
    }
  }
  #pragma unroll
  for (int g = 0; g < 4; ++g){
    int r = rbase + r0 + g;
    if (r < NN){
      float sc = dis[r];
      float4 o;
      o.x = acc[g][0]*sc; o.y = acc[g][1]*sc;
      o.z = acc[g][2]*sc; o.w = acc[g][3]*sc;
      *(float4*)&h2s[(size_t)r*EM + c0] = o;
    }
  }
}

// -- GCN2 gather: same uniform-shfl structure, 4 subs of 16 lanes -----------
__global__ __launch_bounds__(256) void k_gather2(
    const int* __restrict__ rowptr, const int* __restrict__ esrc,
    const float* __restrict__ dis, const float* __restrict__ h2s,
    const float* __restrict__ b2v, float* __restrict__ out){
  int w = threadIdx.x >> 6, lane = threadIdx.x & 63;
  int d = blockIdx.x*4 + w;
  int sub = lane >> 4;
  int q = lane & 15;
  float dd = dis[d];
  float4 a = make_float4(0.f,0.f,0.f,0.f);
  if (sub == 0){
    a = *(const float4*)&h2s[(size_t)d*EM + q*4];   // self loop (dd applied at end)
  }
  int p0 = rowptr[d], p1 = rowptr[d+1];
  for (int base = p0; base < p1; base += 64){
    int idx = base + lane;
    int s_l = (idx < p1) ? esrc[idx] : 0;
    int m = min(64, p1 - base);             // wave-uniform
    int mm16 = m & ~15;
    for (int jb = 0; jb < mm16; jb += 16){
      int s0 = __shfl(s_l, jb + sub);
      int s1 = __shfl(s_l, jb + 4 + sub);
      int s2 = __shfl(s_l, jb + 8 + sub);
      int s3 = __shfl(s_l, jb + 12 + sub);
      float4 v0 = *(const float4*)&h2s[(size_t)s0*EM + q*4];
      float4 v1 = *(const float4*)&h2s[(size_t)s1*EM + q*4];
      float4 v2 = *(const float4*)&h2s[(size_t)s2*EM + q*4];
      float4 v3 = *(const float4*)&h2s[(size_t)s3*EM + q*4];
      a.x += v0.x + v1.x + v2.x + v3.x;
      a.y += v0.y + v1.y + v2.y + v3.y;
      a.z += v0.z + v1.z + v2.z + v3.z;
      a.w += v0.w + v1.w + v2.w + v3.w;
    }
    // tail (<16): uniform loop; shfl index clamped to stay in-range
    for (int j = mm16; j < m; j += 4){
      int jj = j + sub;
      int s = __shfl(s_l, min(jj, 63));
      if (jj < m){
        float4 v = *(const float4*)&h2s[(size_t)s*EM + q*4];
        a.x += v.x; a.y += v.y; a.z += v.z; a.w += v.w;
      }
    }
  }
  a.x += __shfl_xor(a.x, 32); a.y += __shfl_xor(a.y, 32);
  a.z += __shfl_xor(a.z, 32); a.w += __shfl_xor(a.w, 32);
  a.x += __shfl_xor(a.x, 16); a.y += __shfl_xor(a.y, 16);
  a.z += __shfl_xor(a.z, 16); a.w += __shfl_xor(a.w, 16);
  if (sub == 0){
    float4 b = *(const float4*)&b2v[q*4];
    a.x = a.x*dd + b.x; a.y = a.y*dd + b.y;
    a.z = a.z*dd + b.z; a.w = a.w*dd + b.w;
    *(float4*)&out[(size_t)d*EM + q*4] = a;   // emb block of out (softmax reads this)
  }
}

// ---- logits + softmax: 32 rows/block, centers streamed from L1, 8 rows/wave --
__global__ __launch_bounds__(256, 4) void k_softmax(const float* __restrict__ embf,
                          const float* __restrict__ centers,
                          const float* __restrict__ temp,
                          float* __restrict__ out){
  __shared__ float er[SROWS][EM];        // 8 KB
  int t = threadIdx.x, w = t >> 6, lane = t & 63;
  int rbase = blockIdx.x * SROWS;        // NN % 32 == 0
  #pragma unroll
  for (int i = 0; i < 2; ++i){
    int flat = (i*256 + t)*4;
    int r = flat >> 6, c = flat & 63;
    *(float4*)&er[r][c] = *(const float4*)&embf[(size_t)(rbase+r)*EM + c];
  }
  __syncthreads();
  int c0 = lane;
  int c1 = (lane < KC-64) ? lane + 64 : KC-1;
  const float* C0 = centers + c0*EM;     // 25.6 KB total -> L1-resident
  const float* C1 = centers + c1*EM;
  float acc0[8] = {}, acc1[8] = {};
  #pragma unroll 4
  for (int k4 = 0; k4 < 16; ++k4){
    float4 a0 = *(const float4*)&C0[k4*4];
    float4 a1 = *(const float4*)&C1[k4*4];
    #pragma unroll
    for (int r = 0; r < 8; ++r){
      float4 ev = *(const float4*)&er[w*8 + r][k4*4];   // broadcast ds_read
      acc0[r] += ev.x*a0.x + ev.y*a0.y + ev.z*a0.z + ev.w*a0.w;
      acc1[r] += ev.x*a1.x + ev.y*a1.y + ev.z*a1.z + ev.w*a1.w;
    }
  }
  float invT = 1.0f / temp[0];
  #pragma unroll
  for (int r = 0; r < 8; ++r){
    float lg0 = acc0[r] * invT;
    float lg1 = (lane < KC-64) ? acc1[r] * invT : -1e30f;
    float m = fmaxf(lg0, lg1);
    #pragma unroll
    for (int off = 32; off > 0; off >>= 1) m = fmaxf(m, __shfl_xor(m, off));
    float e0 = __expf(lg0 - m);
    float e1 = (lane < KC-64) ? __expf(lg1 - m) : 0.f;
    float ssum = e0 + e1;
    #pragma unroll
    for (int off = 32; off > 0; off >>= 1) ssum += __shfl_xor(ssum, off);
    float inv = 1.0f / ssum;
    int row = rbase + w*8 + r;
    float* orow = out + (size_t)NN*EM + (size_t)row*KC;
    orow[lane] = e0 * inv;
    if (lane < KC-64) orow[64 + lane] = e1 * inv;
  }
}

// ---------------- launch ----------------
extern "C" void kernel_launch(void* const* d_in, const int* in_sizes, int n_in,
                              void* d_out, int out_size, void* d_ws, size_t ws_size,
                              hipStream_t stream){
  const float* x      = (const float*)d_in[0];
  const int*   ei     = (const int*)d_in[1];
  const float* W1     = (const float*)d_in[2];
  const float* b1     = (const float*)d_in[3];
  const float* gamma  = (const float*)d_in[4];
  const float* beta   = (const float*)d_in[5];
  const float* W2     = (const float*)d_in[6];
  const float* b2v    = (const float*)d_in[7];
  const float* ctr    = (const float*)d_in[8];
  const float* temp   = (const float*)d_in[9];
  float* out = (float*)d_out;

  // ws: dis[NN] | bufA[NN*HD] | bufB[NN*HD] | sums,sumsq,scale,shift[HD] |
  //     rowptr[NN+1] | esrc[EE] | gcnt[256] bbase[257] gcur[256]
  // pbuf (int2[EE]) overlays bufB (dead until gather1 writes hg).
  float* ws     = (float*)d_ws;
  float* dis    = ws;
  float* bufA   = dis + NN;
  float* bufB   = bufA + (size_t)NN*HD;
  float* sums   = bufB + (size_t)NN*HD;
  float* sumsq  = sums + HD;
  float* scale  = sumsq + HD;
  float* shift  = scale + HD;
  int*   rowptr = (int*)(shift + HD);
  int*   esrc   = rowptr + NN + 1;
  int*   gcnt   = esrc + EE;
  int*   bbase  = gcnt + 256;
  int*   gcur   = bbase + 257;
  int2*  pbuf   = (int2*)bufB;

  float* h1s  = bufA;
  float* hg   = bufB;
  float* h2s  = bufA;

  k_zero256<<<1, 256, 0, stream>>>(gcnt);
  k_bhist  <<<(EE+2047)/2048, 256, 0, stream>>>(ei, gcnt);
  k_bscan  <<<1, 256, 0, stream>>>(gcnt, bbase, gcur, rowptr);
  k_part   <<<(EE+2047)/2048, 256, 0, stream>>>(ei, gcur, pbuf);
  k_bfill  <<<NBK, 256, 0, stream>>>(pbuf, bbase, rowptr, esrc, dis);

  k_gemm1  <<<(NN+63)/64, 256, 0, stream>>>(x, W1, dis, h1s);
  k_gather1<<<NN/4, 256, 0, stream>>>(rowptr, esrc, dis, h1s, b1, hg);

  k_stats_zero<<<1, 128, 0, stream>>>(sums, sumsq);
  k_bn_stats<<<(NN+BN_ROWS-1)/BN_ROWS, 128, 0, stream>>>(hg, sums, sumsq);
  k_bn_coef <<<1, 128, 0, stream>>>(sums, sumsq, gamma, beta, scale, shift);

  k_gemm2  <<<(NN+63)/64, 256, 0, stream>>>(hg, W2, scale, shift, dis, h2s);
  k_gather2<<<NN/4, 256, 0, stream>>>(rowptr, esrc, dis, h2s, b2v, out);

  k_softmax<<<NN/SROWS, 256, 0, stream>>>(out, ctr, temp, out);
}

// Round 3
// 538.892 us; speedup vs baseline: 1.1788x; 1.1532x over previous
//
#include <hip/hip_runtime.h>
#include <hip/hip_bf16.h>

#define NN 100000
#define EE 1600000
#define IND 128
#define HD 128
#define EM 64
#define KC 100
#define BN_EPS 1e-5f
#define BN_ROWS 128
#define BKT 512
#define NBK ((NN + BKT - 1) / BKT)      // 196 buckets (dst >> 9)
#define SROWS 32                         // softmax rows per block

// bf16 helpers: pack two floats (RNE) into one uint; unpack-accumulate.
__device__ __forceinline__ unsigned bf16pk(float lo, float hi){
  unsigned a = __float_as_uint(lo), b = __float_as_uint(hi);
  a += 0x7fffu + ((a >> 16) & 1u);
  b += 0x7fffu + ((b >> 16) & 1u);
  return (a >> 16) | (b & 0xffff0000u);
}
__device__ __forceinline__ void bfacc(float4& a, uint2 v){
  a.x += __uint_as_float(v.x << 16);
  a.y += __uint_as_float(v.x & 0xffff0000u);
  a.z += __uint_as_float(v.y << 16);
  a.w += __uint_as_float(v.y & 0xffff0000u);
}

// ---------------- bucketed CSR build ----------------
__global__ void k_zero256(int* __restrict__ gcnt){
  int t = threadIdx.x;
  if (t < NBK) gcnt[t] = 0;
}

__global__ __launch_bounds__(256) void k_bhist(const int* __restrict__ ei,
                                               int* __restrict__ gcnt){
  __shared__ int lh[NBK];
  int t = threadIdx.x;
  for (int i = t; i < NBK; i += 256) lh[i] = 0;
  __syncthreads();
  int e = blockIdx.x*2048 + t;
  #pragma unroll
  for (int i = 0; i < 8; ++i, e += 256)
    if (e < EE) atomicAdd(&lh[ei[EE + e] >> 9], 1);
  __syncthreads();
  for (int i = t; i < NBK; i += 256)
    if (lh[i]) atomicAdd(&gcnt[i], lh[i]);
}

__global__ void k_bscan(const int* __restrict__ gcnt, int* __restrict__ bbase,
                        int* __restrict__ gcur, int* __restrict__ rowptr){
  __shared__ int ls[256];
  int t = threadIdx.x;
  int v = (t < NBK) ? gcnt[t] : 0;
  ls[t] = v; __syncthreads();
  #pragma unroll
  for (int off = 1; off < 256; off <<= 1){
    int x = (t >= off) ? ls[t-off] : 0;
    __syncthreads();
    ls[t] += x;
    __syncthreads();
  }
  int ex = ls[t] - v;
  if (t < NBK){ bbase[t] = ex; gcur[t] = ex; }
  if (t == NBK-1) bbase[NBK] = ex + v;   // == EE
  if (t == 0) rowptr[NN] = EE;
}

__global__ __launch_bounds__(256) void k_part(const int* __restrict__ ei,
                                              int* __restrict__ gcur,
                                              int2* __restrict__ pbuf){
  __shared__ int lh[NBK];
  __shared__ int lcur[NBK];
  int t = threadIdx.x;
  for (int i = t; i < NBK; i += 256) lh[i] = 0;
  __syncthreads();
  int e0 = blockIdx.x*2048;
  #pragma unroll
  for (int i = 0; i < 8; ++i){
    int e = e0 + i*256 + t;
    if (e < EE) atomicAdd(&lh[ei[EE + e] >> 9], 1);
  }
  __syncthreads();
  for (int i = t; i < NBK; i += 256)
    lcur[i] = lh[i] ? atomicAdd(&gcur[i], lh[i]) : 0;
  __syncthreads();
  #pragma unroll
  for (int i = 0; i < 8; ++i){
    int e = e0 + i*256 + t;
    if (e < EE){
      int s = ei[e], d = ei[EE + e];
      int pos = atomicAdd(&lcur[d >> 9], 1);
      pbuf[pos] = make_int2(s, d);
    }
  }
}

// one block per bucket: LDS hist + local scan + local-cursor fill
__global__ __launch_bounds__(256) void k_bfill(const int2* __restrict__ pbuf,
                                               const int* __restrict__ bbase,
                                               int* __restrict__ rowptr,
                                               int* __restrict__ esrc,
                                               float* __restrict__ dis){
  __shared__ int lcnt[BKT];
  __shared__ int ls[256];
  int b = blockIdx.x, t = threadIdx.x;
  int n0 = b*BKT;
  int e0 = bbase[b], e1 = bbase[b+1];
  lcnt[2*t] = 0; lcnt[2*t+1] = 0;
  __syncthreads();
  for (int e = e0 + t; e < e1; e += 256)
    atomicAdd(&lcnt[pbuf[e].y - n0], 1);
  __syncthreads();
  int v0 = lcnt[2*t], v1 = lcnt[2*t+1];
  int s = v0 + v1;
  ls[t] = s; __syncthreads();
  #pragma unroll
  for (int off = 1; off < 256; off <<= 1){
    int x = (t >= off) ? ls[t-off] : 0;
    __syncthreads();
    ls[t] += x;
    __syncthreads();
  }
  int run = ls[t] - s;                    // exclusive prefix (pairs)
  if (n0 + 2*t < NN){
    rowptr[n0 + 2*t] = e0 + run;
    dis[n0 + 2*t] = rsqrtf((float)v0 + 1.0f);
  }
  if (n0 + 2*t + 1 < NN){
    rowptr[n0 + 2*t + 1] = e0 + run + v0;
    dis[n0 + 2*t + 1] = rsqrtf((float)v1 + 1.0f);
  }
  lcnt[2*t] = run; lcnt[2*t+1] = run + v0;  // relative cursors
  __syncthreads();
  for (int e = e0 + t; e < e1; e += 256){
    int2 p = pbuf[e];
    int pos = atomicAdd(&lcnt[p.y - n0], 1);
    esrc[e0 + pos] = p.x;
  }
}

// ------- GEMM1: h1s = bf16( (x @ W1) * dis[row] )  (pre-scaled, compressed) --
__global__ __launch_bounds__(256) void k_gemm1(const float* __restrict__ x,
                                               const float* __restrict__ W1,
                                               const float* __restrict__ dis,
                                               unsigned short* __restrict__ h1s){
  __shared__ float xs[64][IND];
  int t = threadIdx.x;
  int rbase = blockIdx.x * 64;
  #pragma unroll
  for (int i = 0; i < 8; ++i){
    int flat = i*256 + t;
    int r = flat >> 5;
    int q = flat & 31;
    float4 v = make_float4(0.f,0.f,0.f,0.f);
    if (rbase + r < NN) v = *(const float4*)&x[(size_t)(rbase+r)*IND + q*4];
    *(float4*)&xs[r][q*4] = v;
  }
  __syncthreads();
  int c0 = (t & 31) * 4;
  int r0 = (t >> 5) * 8;
  float acc[8][4] = {};
  #pragma unroll 4
  for (int k4 = 0; k4 < IND/4; ++k4){
    float4 w0 = *(const float4*)&W1[(k4*4+0)*HD + c0];
    float4 w1 = *(const float4*)&W1[(k4*4+1)*HD + c0];
    float4 w2 = *(const float4*)&W1[(k4*4+2)*HD + c0];
    float4 w3 = *(const float4*)&W1[(k4*4+3)*HD + c0];
    #pragma unroll
    for (int g = 0; g < 8; ++g){
      float4 xv = *(const float4*)&xs[r0+g][k4*4];
      acc[g][0] += xv.x*w0.x + xv.y*w1.x + xv.z*w2.x + xv.w*w3.x;
      acc[g][1] += xv.x*w0.y + xv.y*w1.y + xv.z*w2.y + xv.w*w3.y;
      acc[g][2] += xv.x*w0.z + xv.y*w1.z + xv.z*w2.z + xv.w*w3.z;
      acc[g][3] += xv.x*w0.w + xv.y*w1.w + xv.z*w2.w + xv.w*w3.w;
    }
  }
  #pragma unroll
  for (int g = 0; g < 8; ++g){
    int r = rbase + r0 + g;
    if (r < NN){
      float sc = dis[r];
      uint2 o;
      o.x = bf16pk(acc[g][0]*sc, acc[g][1]*sc);
      o.y = bf16pk(acc[g][2]*sc, acc[g][3]*sc);
      *(uint2*)&h1s[(size_t)r*HD + c0] = o;
    }
  }
}

// ---- GCN1 gather: 1 wave/node, bf16 rows (256 B), uniform-shfl broadcast ---
__global__ __launch_bounds__(256) void k_gather1(
    const int* __restrict__ rowptr, const int* __restrict__ esrc,
    const float* __restrict__ dis, const unsigned short* __restrict__ h1s,
    const float* __restrict__ b1, float* __restrict__ hg){
  int w = threadIdx.x >> 6, lane = threadIdx.x & 63;
  int d = blockIdx.x*4 + w;
  int half = lane >> 5;
  int q = lane & 31;
  float dd = dis[d];
  float4 a = make_float4(0.f,0.f,0.f,0.f);
  if (half == 0){
    // self loop: dd*dd*h1[d] == dd * h1s[d]; dd applied at the end
    bfacc(a, *(const uint2*)&h1s[(size_t)d*HD + q*4]);
  }
  int p0 = rowptr[d], p1 = rowptr[d+1];
  for (int base = p0; base < p1; base += 64){
    int idx = base + lane;
    int s_l = (idx < p1) ? esrc[idx] : 0;   // coalesced: 64 edge indices
    int m = min(64, p1 - base);             // wave-uniform
    int mm8 = m & ~7;
    for (int jb = 0; jb < mm8; jb += 8){
      int s0 = __shfl(s_l, jb + half);
      int s1 = __shfl(s_l, jb + 2 + half);
      int s2 = __shfl(s_l, jb + 4 + half);
      int s3 = __shfl(s_l, jb + 6 + half);
      uint2 v0 = *(const uint2*)&h1s[(size_t)s0*HD + q*4];
      uint2 v1 = *(const uint2*)&h1s[(size_t)s1*HD + q*4];
      uint2 v2 = *(const uint2*)&h1s[(size_t)s2*HD + q*4];
      uint2 v3 = *(const uint2*)&h1s[(size_t)s3*HD + q*4];
      bfacc(a, v0); bfacc(a, v1); bfacc(a, v2); bfacc(a, v3);
    }
    for (int j = mm8; j < m; j += 2){
      int jj = j + half;                    // jj <= m <= 63 here
      int s = __shfl(s_l, jj);
      if (jj < m){
        bfacc(a, *(const uint2*)&h1s[(size_t)s*HD + q*4]);
      }
    }
  }
  a.x += __shfl_xor(a.x, 32); a.y += __shfl_xor(a.y, 32);
  a.z += __shfl_xor(a.z, 32); a.w += __shfl_xor(a.w, 32);
  if (half == 0){
    float4 b = *(const float4*)&b1[q*4];
    a.x = a.x*dd + b.x; a.y = a.y*dd + b.y;
    a.z = a.z*dd + b.z; a.w = a.w*dd + b.w;
    *(float4*)&hg[(size_t)d*HD + q*4] = a;
  }
}

// ---------------- BatchNorm stats + coefficients ----------------
__global__ void k_stats_zero(float* __restrict__ sums, float* __restrict__ sumsq){
  int i = threadIdx.x;
  if (i < HD){ sums[i] = 0.f; sumsq[i] = 0.f; }
}

__global__ void k_bn_stats(const float* __restrict__ hg, float* __restrict__ sums,
                           float* __restrict__ sumsq){
  int j = threadIdx.x;
  int r0 = blockIdx.x * BN_ROWS;
  int r1 = min(r0 + BN_ROWS, NN);
  float s = 0.f, q = 0.f;
  for (int r = r0; r < r1; ++r){
    float v = hg[(size_t)r*HD + j];
    s += v; q += v*v;
  }
  atomicAdd(&sums[j], s);
  atomicAdd(&sumsq[j], q);
}

__global__ void k_bn_coef(const float* __restrict__ sums, const float* __restrict__ sumsq,
                          const float* __restrict__ gamma, const float* __restrict__ beta,
                          float* __restrict__ scale, float* __restrict__ shift){
  int j = threadIdx.x;
  const float invN = 1.0f/(float)NN;
  float mu  = sums[j]*invN;
  float var = sumsq[j]*invN - mu*mu;
  float sc  = gamma[j]*rsqrtf(var+BN_EPS);
  scale[j] = sc;
  shift[j] = beta[j] - mu*sc;
}

// ------- GEMM2: h2s = bf16( (relu(bn(hg)) @ W2) * dis[row] ) ----------
__global__ __launch_bounds__(256) void k_gemm2(const float* __restrict__ hg,
                                               const float* __restrict__ W2,
                                               const float* __restrict__ scale,
                                               const float* __restrict__ shift,
                                               const float* __restrict__ dis,
                                               unsigned short* __restrict__ h2s){
  __shared__ float hs[64][HD];
  int t = threadIdx.x;
  int rbase = blockIdx.x * 64;
  #pragma unroll
  for (int i = 0; i < 8; ++i){
    int flat = i*256 + t;
    int r = flat >> 5;
    int q = flat & 31;
    float4 v = make_float4(0.f,0.f,0.f,0.f);
    if (rbase + r < NN){
      v = *(const float4*)&hg[(size_t)(rbase+r)*HD + q*4];
      float4 sc = *(const float4*)&scale[q*4];
      float4 sh = *(const float4*)&shift[q*4];
      v.x = fmaxf(v.x*sc.x + sh.x, 0.f);
      v.y = fmaxf(v.y*sc.y + sh.y, 0.f);
      v.z = fmaxf(v.z*sc.z + sh.z, 0.f);
      v.w = fmaxf(v.w*sc.w + sh.w, 0.f);
    }
    *(float4*)&hs[r][q*4] = v;
  }
  __syncthreads();
  int c0 = (t & 15) * 4;
  int r0 = (t >> 4) * 4;
  float acc[4][4] = {};
  #pragma unroll 4
  for (int k4 = 0; k4 < HD/4; ++k4){
    float4 w0 = *(const float4*)&W2[(k4*4+0)*EM + c0];
    float4 w1 = *(const float4*)&W2[(k4*4+1)*EM + c0];
    float4 w2 = *(const float4*)&W2[(k4*4+2)*EM + c0];
    float4 w3 = *(const float4*)&W2[(k4*4+3)*EM + c0];
    #pragma unroll
    for (int g = 0; g < 4; ++g){
      float4 xv = *(const float4*)&hs[r0+g][k4*4];
      acc[g][0] += xv.x*w0.x + xv.y*w1.x + xv.z*w2.x + xv.w*w3.x;
      acc[g][1] += xv.x*w0.y + xv.y*w1.y + xv.z*w2.y + xv.w*w3.y;
      acc[g][2] += xv.x*w0.z + xv.y*w1.z + xv.z*w2.z + xv.w*w3.z;
      acc[g][3] += xv.x*w0.w + xv.y*w1.w + xv.z*w2.w + xv.w*w3.w;
    }
  }
  #pragma unroll
  for (int g = 0; g < 4; ++g){
    int r = rbase + r0 + g;
    if (r < NN){
      float sc = dis[r];
      uint2 o;
      o.x = bf16pk(acc[g][0]*sc, acc[g][1]*sc);
      o.y = bf16pk(acc[g][2]*sc, acc[g][3]*sc);
      *(uint2*)&h2s[(size_t)r*EM + c0] = o;
    }
  }
}

// -- GCN2 gather: bf16 rows (128 B), 4 subs of 16 lanes, uniform shfl --------
__global__ __launch_bounds__(256) void k_gather2(
    const int* __restrict__ rowptr, const int* __restrict__ esrc,
    const float* __restrict__ dis, const unsigned short* __restrict__ h2s,
    const float* __restrict__ b2v, float* __restrict__ out){
  int w = threadIdx.x >> 6, lane = threadIdx.x & 63;
  int d = blockIdx.x*4 + w;
  int sub = lane >> 4;
  int q = lane & 15;
  float dd = dis[d];
  float4 a = make_float4(0.f,0.f,0.f,0.f);
  if (sub == 0){
    bfacc(a, *(const uint2*)&h2s[(size_t)d*EM + q*4]);   // self loop
  }
  int p0 = rowptr[d], p1 = rowptr[d+1];
  for (int base = p0; base < p1; base += 64){
    int idx = base + lane;
    int s_l = (idx < p1) ? esrc[idx] : 0;
    int m = min(64, p1 - base);             // wave-uniform
    int mm16 = m & ~15;
    for (int jb = 0; jb < mm16; jb += 16){
      int s0 = __shfl(s_l, jb + sub);
      int s1 = __shfl(s_l, jb + 4 + sub);
      int s2 = __shfl(s_l, jb + 8 + sub);
      int s3 = __shfl(s_l, jb + 12 + sub);
      uint2 v0 = *(const uint2*)&h2s[(size_t)s0*EM + q*4];
      uint2 v1 = *(const uint2*)&h2s[(size_t)s1*EM + q*4];
      uint2 v2 = *(const uint2*)&h2s[(size_t)s2*EM + q*4];
      uint2 v3 = *(const uint2*)&h2s[(size_t)s3*EM + q*4];
      bfacc(a, v0); bfacc(a, v1); bfacc(a, v2); bfacc(a, v3);
    }
    for (int j = mm16; j < m; j += 4){
      int jj = j + sub;
      int s = __shfl(s_l, min(jj, 63));
      if (jj < m){
        bfacc(a, *(const uint2*)&h2s[(size_t)s*EM + q*4]);
      }
    }
  }
  a.x += __shfl_xor(a.x, 32); a.y += __shfl_xor(a.y, 32);
  a.z += __shfl_xor(a.z, 32); a.w += __shfl_xor(a.w, 32);
  a.x += __shfl_xor(a.x, 16); a.y += __shfl_xor(a.y, 16);
  a.z += __shfl_xor(a.z, 16); a.w += __shfl_xor(a.w, 16);
  if (sub == 0){
    float4 b = *(const float4*)&b2v[q*4];
    a.x = a.x*dd + b.x; a.y = a.y*dd + b.y;
    a.z = a.z*dd + b.z; a.w = a.w*dd + b.w;
    *(float4*)&out[(size_t)d*EM + q*4] = a;   // emb block of out
  }
}

// ---- logits + softmax: 32 rows/block, centers streamed from L1, 8 rows/wave --
__global__ __launch_bounds__(256, 4) void k_softmax(const float* __restrict__ embf,
                          const float* __restrict__ centers,
                          const float* __restrict__ temp,
                          float* __restrict__ out){
  __shared__ float er[SROWS][EM];        // 8 KB
  int t = threadIdx.x, w = t >> 6, lane = t & 63;
  int rbase = blockIdx.x * SROWS;        // NN % 32 == 0
  #pragma unroll
  for (int i = 0; i < 2; ++i){
    int flat = (i*256 + t)*4;
    int r = flat >> 6, c = flat & 63;
    *(float4*)&er[r][c] = *(const float4*)&embf[(size_t)(rbase+r)*EM + c];
  }
  __syncthreads();
  int c0 = lane;
  int c1 = (lane < KC-64) ? lane + 64 : KC-1;
  const float* C0 = centers + c0*EM;     // 25.6 KB total -> L1-resident
  const float* C1 = centers + c1*EM;
  float acc0[8] = {}, acc1[8] = {};
  #pragma unroll 4
  for (int k4 = 0; k4 < 16; ++k4){
    float4 a0 = *(const float4*)&C0[k4*4];
    float4 a1 = *(const float4*)&C1[k4*4];
    #pragma unroll
    for (int r = 0; r < 8; ++r){
      float4 ev = *(const float4*)&er[w*8 + r][k4*4];   // broadcast ds_read
      acc0[r] += ev.x*a0.x + ev.y*a0.y + ev.z*a0.z + ev.w*a0.w;
      acc1[r] += ev.x*a1.x + ev.y*a1.y + ev.z*a1.z + ev.w*a1.w;
    }
  }
  float invT = 1.0f / temp[0];
  #pragma unroll
  for (int r = 0; r < 8; ++r){
    float lg0 = acc0[r] * invT;
    float lg1 = (lane < KC-64) ? acc1[r] * invT : -1e30f;
    float m = fmaxf(lg0, lg1);
    #pragma unroll
    for (int off = 32; off > 0; off >>= 1) m = fmaxf(m, __shfl_xor(m, off));
    float e0 = __expf(lg0 - m);
    float e1 = (lane < KC-64) ? __expf(lg1 - m) : 0.f;
    float ssum = e0 + e1;
    #pragma unroll
    for (int off = 32; off > 0; off >>= 1) ssum += __shfl_xor(ssum, off);
    float inv = 1.0f / ssum;
    int row = rbase + w*8 + r;
    float* orow = out + (size_t)NN*EM + (size_t)row*KC;
    orow[lane] = e0 * inv;
    if (lane < KC-64) orow[64 + lane] = e1 * inv;
  }
}

// ---------------- launch ----------------
extern "C" void kernel_launch(void* const* d_in, const int* in_sizes, int n_in,
                              void* d_out, int out_size, void* d_ws, size_t ws_size,
                              hipStream_t stream){
  const float* x      = (const float*)d_in[0];
  const int*   ei     = (const int*)d_in[1];
  const float* W1     = (const float*)d_in[2];
  const float* b1     = (const float*)d_in[3];
  const float* gamma  = (const float*)d_in[4];
  const float* beta   = (const float*)d_in[5];
  const float* W2     = (const float*)d_in[6];
  const float* b2v    = (const float*)d_in[7];
  const float* ctr    = (const float*)d_in[8];
  const float* temp   = (const float*)d_in[9];
  float* out = (float*)d_out;

  // ws: dis[NN] | bufA[NN*HD] | bufB[NN*HD] | sums,sumsq,scale,shift[HD] |
  //     rowptr[NN+1] | esrc[EE] | gcnt[256] bbase[257] gcur[256]
  // h1s/h2s (bf16) live in bufA; pbuf (int2[EE]) overlays bufB (dead until
  // gather1 writes hg).
  float* ws     = (float*)d_ws;
  float* dis    = ws;
  float* bufA   = dis + NN;
  float* bufB   = bufA + (size_t)NN*HD;
  float* sums   = bufB + (size_t)NN*HD;
  float* sumsq  = sums + HD;
  float* scale  = sumsq + HD;
  float* shift  = scale + HD;
  int*   rowptr = (int*)(shift + HD);
  int*   esrc   = rowptr + NN + 1;
  int*   gcnt   = esrc + EE;
  int*   bbase  = gcnt + 256;
  int*   gcur   = bbase + 257;
  int2*  pbuf   = (int2*)bufB;

  unsigned short* h1s = (unsigned short*)bufA;
  float*          hg  = bufB;
  unsigned short* h2s = (unsigned short*)bufA;

  k_zero256<<<1, 256, 0, stream>>>(gcnt);
  k_bhist  <<<(EE+2047)/2048, 256, 0, stream>>>(ei, gcnt);
  k_bscan  <<<1, 256, 0, stream>>>(gcnt, bbase, gcur, rowptr);
  k_part   <<<(EE+2047)/2048, 256, 0, stream>>>(ei, gcur, pbuf);
  k_bfill  <<<NBK, 256, 0, stream>>>(pbuf, bbase, rowptr, esrc, dis);

  k_gemm1  <<<(NN+63)/64, 256, 0, stream>>>(x, W1, dis, h1s);
  k_gather1<<<NN/4, 256, 0, stream>>>(rowptr, esrc, dis, h1s, b1, hg);

  k_stats_zero<<<1, 128, 0, stream>>>(sums, sumsq);
  k_bn_stats<<<(NN+BN_ROWS-1)/BN_ROWS, 128, 0, stream>>>(hg, sums, sumsq);
  k_bn_coef <<<1, 128, 0, stream>>>(sums, sumsq, gamma, beta, scale, shift);

  k_gemm2  <<<(NN+63)/64, 256, 0, stream>>>(hg, W2, scale, shift, dis, h2s);
  k_gather2<<<NN/4, 256, 0, stream>>>(rowptr, esrc, dis, h2s, b2v, out);

  k_softmax<<<NN/SROWS, 256, 0, stream>>>(out, ctr, temp, out);
}

// Round 6
// 471.308 us; speedup vs baseline: 1.3479x; 1.1434x over previous
//
#include <hip/hip_runtime.h>
#include <hip/hip_bf16.h>
#include <stdint.h>

#define NN 100000
#define EE 1600000
#define IND 128
#define HD 128
#define EM 64
#define KC 100
#define BN_EPS 1e-5f
#define BN_ROWS 128
#define BKT 512
#define NBK ((NN + BKT - 1) / BKT)      // 196 buckets (dst >> 9)
#define SROWS 32                         // softmax rows per block

typedef _Float16 h8 __attribute__((ext_vector_type(8)));
typedef float f4v __attribute__((ext_vector_type(4)));

// bf16 helpers: pack two floats (RNE) into one uint; unpack-accumulate.
__device__ __forceinline__ unsigned bf16pk(float lo, float hi){
  unsigned a = __float_as_uint(lo), b = __float_as_uint(hi);
  a += 0x7fffu + ((a >> 16) & 1u);
  b += 0x7fffu + ((b >> 16) & 1u);
  return (a >> 16) | (b & 0xffff0000u);
}
__device__ __forceinline__ unsigned short bf16s(float v){
  unsigned u = __float_as_uint(v);
  u += 0x7fffu + ((u >> 16) & 1u);
  return (unsigned short)(u >> 16);
}
__device__ __forceinline__ void bfacc(float4& a, uint2 v){
  a.x += __uint_as_float(v.x << 16);
  a.y += __uint_as_float(v.x & 0xffff0000u);
  a.z += __uint_as_float(v.y << 16);
  a.w += __uint_as_float(v.y & 0xffff0000u);
}

// ---------------- bucketed CSR build ----------------
__global__ void k_zero256(int* __restrict__ gcnt){
  int t = threadIdx.x;
  if (t < NBK) gcnt[t] = 0;
}

__global__ __launch_bounds__(256) void k_bhist(const int* __restrict__ ei,
                                               int* __restrict__ gcnt){
  __shared__ int lh[NBK];
  int t = threadIdx.x;
  for (int i = t; i < NBK; i += 256) lh[i] = 0;
  __syncthreads();
  int e = blockIdx.x*2048 + t;
  #pragma unroll
  for (int i = 0; i < 8; ++i, e += 256)
    if (e < EE) atomicAdd(&lh[ei[EE + e] >> 9], 1);
  __syncthreads();
  for (int i = t; i < NBK; i += 256)
    if (lh[i]) atomicAdd(&gcnt[i], lh[i]);
}

__global__ void k_bscan(const int* __restrict__ gcnt, int* __restrict__ bbase,
                        int* __restrict__ gcur, int* __restrict__ rowptr){
  __shared__ int ls[256];
  int t = threadIdx.x;
  int v = (t < NBK) ? gcnt[t] : 0;
  ls[t] = v; __syncthreads();
  #pragma unroll
  for (int off = 1; off < 256; off <<= 1){
    int x = (t >= off) ? ls[t-off] : 0;
    __syncthreads();
    ls[t] += x;
    __syncthreads();
  }
  int ex = ls[t] - v;
  if (t < NBK){ bbase[t] = ex; gcur[t] = ex; }
  if (t == NBK-1) bbase[NBK] = ex + v;   // == EE
  if (t == 0) rowptr[NN] = EE;
}

__global__ __launch_bounds__(256) void k_part(const int* __restrict__ ei,
                                              int* __restrict__ gcur,
                                              int2* __restrict__ pbuf){
  __shared__ int lh[NBK];
  __shared__ int lcur[NBK];
  int t = threadIdx.x;
  for (int i = t; i < NBK; i += 256) lh[i] = 0;
  __syncthreads();
  int e0 = blockIdx.x*2048;
  #pragma unroll
  for (int i = 0; i < 8; ++i){
    int e = e0 + i*256 + t;
    if (e < EE) atomicAdd(&lh[ei[EE + e] >> 9], 1);
  }
  __syncthreads();
  for (int i = t; i < NBK; i += 256)
    lcur[i] = lh[i] ? atomicAdd(&gcur[i], lh[i]) : 0;
  __syncthreads();
  #pragma unroll
  for (int i = 0; i < 8; ++i){
    int e = e0 + i*256 + t;
    if (e < EE){
      int s = ei[e], d = ei[EE + e];
      int pos = atomicAdd(&lcur[d >> 9], 1);
      pbuf[pos] = make_int2(s, d);
    }
  }
}

// one block per bucket: LDS hist + local scan + local-cursor fill
__global__ __launch_bounds__(256) void k_bfill(const int2* __restrict__ pbuf,
                                               const int* __restrict__ bbase,
                                               int* __restrict__ rowptr,
                                               int* __restrict__ esrc,
                                               float* __restrict__ dis){
  __shared__ int lcnt[BKT];
  __shared__ int ls[256];
  int b = blockIdx.x, t = threadIdx.x;
  int n0 = b*BKT;
  int e0 = bbase[b], e1 = bbase[b+1];
  lcnt[2*t] = 0; lcnt[2*t+1] = 0;
  __syncthreads();
  for (int e = e0 + t; e < e1; e += 256)
    atomicAdd(&lcnt[pbuf[e].y - n0], 1);
  __syncthreads();
  int v0 = lcnt[2*t], v1 = lcnt[2*t+1];
  int s = v0 + v1;
  ls[t] = s; __syncthreads();
  #pragma unroll
  for (int off = 1; off < 256; off <<= 1){
    int x = (t >= off) ? ls[t-off] : 0;
    __syncthreads();
    ls[t] += x;
    __syncthreads();
  }
  int run = ls[t] - s;                    // exclusive prefix (pairs)
  if (n0 + 2*t < NN){
    rowptr[n0 + 2*t] = e0 + run;
    dis[n0 + 2*t] = rsqrtf((float)v0 + 1.0f);
  }
  if (n0 + 2*t + 1 < NN){
    rowptr[n0 + 2*t + 1] = e0 + run + v0;
    dis[n0 + 2*t + 1] = rsqrtf((float)v1 + 1.0f);
  }
  lcnt[2*t] = run; lcnt[2*t+1] = run + v0;  // relative cursors
  __syncthreads();
  for (int e = e0 + t; e < e1; e += 256){
    int2 p = pbuf[e];
    int pos = atomicAdd(&lcnt[p.y - n0], 1);
    esrc[e0 + pos] = p.x;
  }
}

// -------- W fragment prep: fp32 W[K=128][N] -> fp16 MFMA-B-frag order --------
// entry = (ks*nt_cnt + nt)*64 + lane; elem j: k = ks*32 + (j>>2)*16 + (lane>>4)*4 + (j&3)
// n = nt*16 + (lane&15).  The SAME k-formula is used for A-frag loads in the
// GEMMs, so any deviation from the HW's true k-map cancels (bijective-k trick).
__global__ void k_wprep(const float* __restrict__ W, int N, int nt_cnt,
                        unsigned short* __restrict__ wf){
  int e = blockIdx.x*256 + threadIdx.x;
  int total = 4*nt_cnt*64;
  if (e >= total) return;
  int lane = e & 63;
  int nt = (e >> 6) % nt_cnt;
  int ks = (e >> 6) / nt_cnt;
  int n = nt*16 + (lane & 15);
  int kb = ks*32 + (lane >> 4)*4;
  unsigned short out[8];
  #pragma unroll
  for (int j = 0; j < 8; ++j){
    int k = kb + (j>>2)*16 + (j&3);
    _Float16 h = (_Float16)W[k*N + n];
    out[j] = *(unsigned short*)&h;
  }
  *(uint4*)&wf[(size_t)e*8] = *(const uint4*)out;
}

// ------- GEMM1 (MFMA f16): h1s = bf16( (x @ W1) * dis[row] ) ----------------
// 64 rows/block, 4 waves x 16 rows. A-frags straight from global x (each load
// covers 16 full 64B sectors); B-frags 16B/lane coalesced from L2-resident w1f.
__global__ __launch_bounds__(256) void k_gemm1(const float* __restrict__ x,
                                               const unsigned short* __restrict__ w1f,
                                               const float* __restrict__ dis,
                                               unsigned short* __restrict__ h1s){
  int t = threadIdx.x, w = t >> 6, l = t & 63;
  int arow = blockIdx.x*64 + w*16 + (l & 15);
  const float* xr = x + (size_t)min(arow, NN-1)*IND;
  int kg = (l >> 4)*4;
  f4v acc[8];
  #pragma unroll
  for (int i = 0; i < 8; ++i) acc[i] = (f4v){0.f,0.f,0.f,0.f};
  #pragma unroll
  for (int ks = 0; ks < 4; ++ks){
    float4 a0 = *(const float4*)&xr[ks*32 + kg];
    float4 a1 = *(const float4*)&xr[ks*32 + 16 + kg];
    h8 af;
    af[0]=(_Float16)a0.x; af[1]=(_Float16)a0.y; af[2]=(_Float16)a0.z; af[3]=(_Float16)a0.w;
    af[4]=(_Float16)a1.x; af[5]=(_Float16)a1.y; af[6]=(_Float16)a1.z; af[7]=(_Float16)a1.w;
    const unsigned short* wb = w1f + ((size_t)(ks*8)*64 + l)*8;
    #pragma unroll
    for (int nt = 0; nt < 8; ++nt){
      h8 bf = *(const h8*)(wb + (size_t)nt*64*8);
      acc[nt] = __builtin_amdgcn_mfma_f32_16x16x32_f16(af, bf, acc[nt], 0, 0, 0);
    }
  }
  int orow0 = blockIdx.x*64 + w*16 + (l >> 4)*4;
  int oc = l & 15;
  #pragma unroll
  for (int r = 0; r < 4; ++r){
    int rr = orow0 + r;
    if (rr < NN){
      float sc = dis[rr];
      #pragma unroll
      for (int nt = 0; nt < 8; ++nt)
        h1s[(size_t)rr*HD + nt*16 + oc] = bf16s(acc[nt][r]*sc);
    }
  }
}

// ---- GCN1 gather: 1 wave/node, bf16 rows (256 B), uniform-shfl broadcast ---
__global__ __launch_bounds__(256) void k_gather1(
    const int* __restrict__ rowptr, const int* __restrict__ esrc,
    const float* __restrict__ dis, const unsigned short* __restrict__ h1s,
    const float* __restrict__ b1, float* __restrict__ hg){
  int w = threadIdx.x >> 6, lane = threadIdx.x & 63;
  int d = blockIdx.x*4 + w;
  int half = lane >> 5;
  int q = lane & 31;
  float dd = dis[d];
  float4 a = make_float4(0.f,0.f,0.f,0.f);
  if (half == 0){
    bfacc(a, *(const uint2*)&h1s[(size_t)d*HD + q*4]);   // self loop
  }
  int p0 = rowptr[d], p1 = rowptr[d+1];
  for (int base = p0; base < p1; base += 64){
    int idx = base + lane;
    int s_l = (idx < p1) ? esrc[idx] : 0;   // coalesced: 64 edge indices
    int m = min(64, p1 - base);             // wave-uniform
    int mm8 = m & ~7;
    for (int jb = 0; jb < mm8; jb += 8){
      int s0 = __shfl(s_l, jb + half);
      int s1 = __shfl(s_l, jb + 2 + half);
      int s2 = __shfl(s_l, jb + 4 + half);
      int s3 = __shfl(s_l, jb + 6 + half);
      uint2 v0 = *(const uint2*)&h1s[(size_t)s0*HD + q*4];
      uint2 v1 = *(const uint2*)&h1s[(size_t)s1*HD + q*4];
      uint2 v2 = *(const uint2*)&h1s[(size_t)s2*HD + q*4];
      uint2 v3 = *(const uint2*)&h1s[(size_t)s3*HD + q*4];
      bfacc(a, v0); bfacc(a, v1); bfacc(a, v2); bfacc(a, v3);
    }
    for (int j = mm8; j < m; j += 2){
      int jj = j + half;                    // jj <= m <= 63 here
      int s = __shfl(s_l, jj);
      if (jj < m){
        bfacc(a, *(const uint2*)&h1s[(size_t)s*HD + q*4]);
      }
    }
  }
  a.x += __shfl_xor(a.x, 32); a.y += __shfl_xor(a.y, 32);
  a.z += __shfl_xor(a.z, 32); a.w += __shfl_xor(a.w, 32);
  if (half == 0){
    float4 b = *(const float4*)&b1[q*4];
    a.x = a.x*dd + b.x; a.y = a.y*dd + b.y;
    a.z = a.z*dd + b.z; a.w = a.w*dd + b.w;
    *(float4*)&hg[(size_t)d*HD + q*4] = a;
  }
}

// ---------------- BatchNorm stats + coefficients ----------------
__global__ void k_stats_zero(float* __restrict__ sums, float* __restrict__ sumsq){
  int i = threadIdx.x;
  if (i < HD){ sums[i] = 0.f; sumsq[i] = 0.f; }
}

__global__ void k_bn_stats(const float* __restrict__ hg, float* __restrict__ sums,
                           float* __restrict__ sumsq){
  int j = threadIdx.x;
  int r0 = blockIdx.x * BN_ROWS;
  int r1 = min(r0 + BN_ROWS, NN);
  float s = 0.f, q = 0.f;
  for (int r = r0; r < r1; ++r){
    float v = hg[(size_t)r*HD + j];
    s += v; q += v*v;
  }
  atomicAdd(&sums[j], s);
  atomicAdd(&sumsq[j], q);
}

__global__ void k_bn_coef(const float* __restrict__ sums, const float* __restrict__ sumsq,
                          const float* __restrict__ gamma, const float* __restrict__ beta,
                          float* __restrict__ scale, float* __restrict__ shift){
  int j = threadIdx.x;
  const float invN = 1.0f/(float)NN;
  float mu  = sums[j]*invN;
  float var = sumsq[j]*invN - mu*mu;
  float sc  = gamma[j]*rsqrtf(var+BN_EPS);
  scale[j] = sc;
  shift[j] = beta[j] - mu*sc;
}

// ------- GEMM2 (MFMA f16): h2s = bf16( (relu(bn(hg)) @ W2) * dis[row] ) -----
__global__ __launch_bounds__(256) void k_gemm2(const float* __restrict__ hg,
                                               const unsigned short* __restrict__ w2f,
                                               const float* __restrict__ scale,
                                               const float* __restrict__ shift,
                                               const float* __restrict__ dis,
                                               unsigned short* __restrict__ h2s){
  int t = threadIdx.x, w = t >> 6, l = t & 63;
  int arow = blockIdx.x*64 + w*16 + (l & 15);
  const float* hr = hg + (size_t)min(arow, NN-1)*HD;
  int kg = (l >> 4)*4;
  f4v acc[4];
  #pragma unroll
  for (int i = 0; i < 4; ++i) acc[i] = (f4v){0.f,0.f,0.f,0.f};
  #pragma unroll
  for (int ks = 0; ks < 4; ++ks){
    float4 a0 = *(const float4*)&hr[ks*32 + kg];
    float4 a1 = *(const float4*)&hr[ks*32 + 16 + kg];
    float4 s0 = *(const float4*)&scale[ks*32 + kg];
    float4 s1 = *(const float4*)&scale[ks*32 + 16 + kg];
    float4 f0 = *(const float4*)&shift[ks*32 + kg];
    float4 f1 = *(const float4*)&shift[ks*32 + 16 + kg];
    h8 af;
    af[0]=(_Float16)fmaxf(a0.x*s0.x+f0.x,0.f);
    af[1]=(_Float16)fmaxf(a0.y*s0.y+f0.y,0.f);
    af[2]=(_Float16)fmaxf(a0.z*s0.z+f0.z,0.f);
    af[3]=(_Float16)fmaxf(a0.w*s0.w+f0.w,0.f);
    af[4]=(_Float16)fmaxf(a1.x*s1.x+f1.x,0.f);
    af[5]=(_Float16)fmaxf(a1.y*s1.y+f1.y,0.f);
    af[6]=(_Float16)fmaxf(a1.z*s1.z+f1.z,0.f);
    af[7]=(_Float16)fmaxf(a1.w*s1.w+f1.w,0.f);
    const unsigned short* wb = w2f + ((size_t)(ks*4)*64 + l)*8;
    #pragma unroll
    for (int nt = 0; nt < 4; ++nt){
      h8 bf = *(const h8*)(wb + (size_t)nt*64*8);
      acc[nt] = __builtin_amdgcn_mfma_f32_16x16x32_f16(af, bf, acc[nt], 0, 0, 0);
    }
  }
  int orow0 = blockIdx.x*64 + w*16 + (l >> 4)*4;
  int oc = l & 15;
  #pragma unroll
  for (int r = 0; r < 4; ++r){
    int rr = orow0 + r;
    if (rr < NN){
      float sc = dis[rr];
      #pragma unroll
      for (int nt = 0; nt < 4; ++nt)
        h2s[(size_t)rr*EM + nt*16 + oc] = bf16s(acc[nt][r]*sc);
    }
  }
}

// -- GCN2 gather: bf16 rows (128 B), 4 subs of 16 lanes, uniform shfl --------
__global__ __launch_bounds__(256) void k_gather2(
    const int* __restrict__ rowptr, const int* __restrict__ esrc,
    const float* __restrict__ dis, const unsigned short* __restrict__ h2s,
    const float* __restrict__ b2v, float* __restrict__ out){
  int w = threadIdx.x >> 6, lane = threadIdx.x & 63;
  int d = blockIdx.x*4 + w;
  int sub = lane >> 4;
  int q = lane & 15;
  float dd = dis[d];
  float4 a = make_float4(0.f,0.f,0.f,0.f);
  if (sub == 0){
    bfacc(a, *(const uint2*)&h2s[(size_t)d*EM + q*4]);   // self loop
  }
  int p0 = rowptr[d], p1 = rowptr[d+1];
  for (int base = p0; base < p1; base += 64){
    int idx = base + lane;
    int s_l = (idx < p1) ? esrc[idx] : 0;
    int m = min(64, p1 - base);             // wave-uniform
    int mm16 = m & ~15;
    for (int jb = 0; jb < mm16; jb += 16){
      int s0 = __shfl(s_l, jb + sub);
      int s1 = __shfl(s_l, jb + 4 + sub);
      int s2 = __shfl(s_l, jb + 8 + sub);
      int s3 = __shfl(s_l, jb + 12 + sub);
      uint2 v0 = *(const uint2*)&h2s[(size_t)s0*EM + q*4];
      uint2 v1 = *(const uint2*)&h2s[(size_t)s1*EM + q*4];
      uint2 v2 = *(const uint2*)&h2s[(size_t)s2*EM + q*4];
      uint2 v3 = *(const uint2*)&h2s[(size_t)s3*EM + q*4];
      bfacc(a, v0); bfacc(a, v1); bfacc(a, v2); bfacc(a, v3);
    }
    for (int j = mm16; j < m; j += 4){
      int jj = j + sub;
      int s = __shfl(s_l, min(jj, 63));
      if (jj < m){
        bfacc(a, *(const uint2*)&h2s[(size_t)s*EM + q*4]);
      }
    }
  }
  a.x += __shfl_xor(a.x, 32); a.y += __shfl_xor(a.y, 32);
  a.z += __shfl_xor(a.z, 32); a.w += __shfl_xor(a.w, 32);
  a.x += __shfl_xor(a.x, 16); a.y += __shfl_xor(a.y, 16);
  a.z += __shfl_xor(a.z, 16); a.w += __shfl_xor(a.w, 16);
  if (sub == 0){
    float4 b = *(const float4*)&b2v[q*4];
    a.x = a.x*dd + b.x; a.y = a.y*dd + b.y;
    a.z = a.z*dd + b.z; a.w = a.w*dd + b.w;
    *(float4*)&out[(size_t)d*EM + q*4] = a;   // emb block of out
  }
}

// ---- logits + softmax: 32 rows/block, centers streamed from L1, 8 rows/wave --
__global__ __launch_bounds__(256, 4) void k_softmax(const float* __restrict__ embf,
                          const float* __restrict__ centers,
                          const float* __restrict__ temp,
                          float* __restrict__ out){
  __shared__ float er[SROWS][EM];        // 8 KB
  int t = threadIdx.x, w = t >> 6, lane = t & 63;
  int rbase = blockIdx.x * SROWS;        // NN % 32 == 0
  #pragma unroll
  for (int i = 0; i < 2; ++i){
    int flat = (i*256 + t)*4;
    int r = flat >> 6, c = flat & 63;
    *(float4*)&er[r][c] = *(const float4*)&embf[(size_t)(rbase+r)*EM + c];
  }
  __syncthreads();
  int c0 = lane;
  int c1 = (lane < KC-64) ? lane + 64 : KC-1;
  const float* C0 = centers + c0*EM;     // 25.6 KB total -> L1-resident
  const float* C1 = centers + c1*EM;
  float acc0[8] = {}, acc1[8] = {};
  #pragma unroll 4
  for (int k4 = 0; k4 < 16; ++k4){
    float4 a0 = *(const float4*)&C0[k4*4];
    float4 a1 = *(const float4*)&C1[k4*4];
    #pragma unroll
    for (int r = 0; r < 8; ++r){
      float4 ev = *(const float4*)&er[w*8 + r][k4*4];   // broadcast ds_read
      acc0[r] += ev.x*a0.x + ev.y*a0.y + ev.z*a0.z + ev.w*a0.w;
      acc1[r] += ev.x*a1.x + ev.y*a1.y + ev.z*a1.z + ev.w*a1.w;
    }
  }
  float invT = 1.0f / temp[0];
  #pragma unroll
  for (int r = 0; r < 8; ++r){
    float lg0 = acc0[r] * invT;
    float lg1 = (lane < KC-64) ? acc1[r] * invT : -1e30f;
    float m = fmaxf(lg0, lg1);
    #pragma unroll
    for (int off = 32; off > 0; off >>= 1) m = fmaxf(m, __shfl_xor(m, off));
    float e0 = __expf(lg0 - m);
    float e1 = (lane < KC-64) ? __expf(lg1 - m) : 0.f;
    float ssum = e0 + e1;
    #pragma unroll
    for (int off = 32; off > 0; off >>= 1) ssum += __shfl_xor(ssum, off);
    float inv = 1.0f / ssum;
    int row = rbase + w*8 + r;
    float* orow = out + (size_t)NN*EM + (size_t)row*KC;
    orow[lane] = e0 * inv;
    if (lane < KC-64) orow[64 + lane] = e1 * inv;
  }
}

// ---------------- launch ----------------
extern "C" void kernel_launch(void* const* d_in, const int* in_sizes, int n_in,
                              void* d_out, int out_size, void* d_ws, size_t ws_size,
                              hipStream_t stream){
  const float* x      = (const float*)d_in[0];
  const int*   ei     = (const int*)d_in[1];
  const float* W1     = (const float*)d_in[2];
  const float* b1     = (const float*)d_in[3];
  const float* gamma  = (const float*)d_in[4];
  const float* beta   = (const float*)d_in[5];
  const float* W2     = (const float*)d_in[6];
  const float* b2v    = (const float*)d_in[7];
  const float* ctr    = (const float*)d_in[8];
  const float* temp   = (const float*)d_in[9];
  float* out = (float*)d_out;

  // ws: dis[NN] | bufA[NN*HD] | bufB[NN*HD] | sums,sumsq,scale,shift[HD] |
  //     rowptr[NN+1] | esrc[EE] | gcnt[256] bbase[257] gcur[256] | w1f | w2f
  // h1s/h2s (bf16) live in bufA; pbuf (int2[EE]) overlays bufB (dead until
  // gather1 writes hg).
  float* ws     = (float*)d_ws;
  float* dis    = ws;
  float* bufA   = dis + NN;
  float* bufB   = bufA + (size_t)NN*HD;
  float* sums   = bufB + (size_t)NN*HD;
  float* sumsq  = sums + HD;
  float* scale  = sumsq + HD;
  float* shift  = scale + HD;
  int*   rowptr = (int*)(shift + HD);
  int*   esrc   = rowptr + NN + 1;
  int*   gcnt   = esrc + EE;
  int*   bbase  = gcnt + 256;
  int*   gcur   = bbase + 257;
  unsigned short* w1f = (unsigned short*)(((uintptr_t)(gcur + 256) + 15) & ~(uintptr_t)15);
  unsigned short* w2f = w1f + 4*8*64*8;   // 16K halves, then 8K halves
  int2*  pbuf   = (int2*)bufB;

  unsigned short* h1s = (unsigned short*)bufA;
  float*          hg  = bufB;
  unsigned short* h2s = (unsigned short*)bufA;

  k_zero256<<<1, 256, 0, stream>>>(gcnt);
  k_wprep  <<<8, 256, 0, stream>>>(W1, HD, 8, w1f);
  k_wprep  <<<4, 256, 0, stream>>>(W2, EM, 4, w2f);
  k_bhist  <<<(EE+2047)/2048, 256, 0, stream>>>(ei, gcnt);
  k_bscan  <<<1, 256, 0, stream>>>(gcnt, bbase, gcur, rowptr);
  k_part   <<<(EE+2047)/2048, 256, 0, stream>>>(ei, gcur, pbuf);
  k_bfill  <<<NBK, 256, 0, stream>>>(pbuf, bbase, rowptr, esrc, dis);

  k_gemm1  <<<(NN+63)/64, 256, 0, stream>>>(x, w1f, dis, h1s);
  k_gather1<<<NN/4, 256, 0, stream>>>(rowptr, esrc, dis, h1s, b1, hg);

  k_stats_zero<<<1, 128, 0, stream>>>(sums, sumsq);
  k_bn_stats<<<(NN+BN_ROWS-1)/BN_ROWS, 128, 0, stream>>>(hg, sums, sumsq);
  k_bn_coef <<<1, 128, 0, stream>>>(sums, sumsq, gamma, beta, scale, shift);

  k_gemm2  <<<(NN+63)/64, 256, 0, stream>>>(hg, w2f, scale, shift, dis, h2s);
  k_gather2<<<NN/4, 256, 0, stream>>>(rowptr, esrc, dis, h2s, b2v, out);

  k_softmax<<<NN/SROWS, 256, 0, stream>>>(out, ctr, temp, out);
}